// Round 5
// baseline (569.490 us; speedup 1.0000x reference)
//
#include <hip/hip_runtime.h>
#include <math.h>

// ---------------- wave helpers ----------------
__device__ __forceinline__ float wred_sum(float v) {
#pragma unroll
  for (int o = 32; o; o >>= 1) v += __shfl_xor(v, o, 64);
  return v;
}
__device__ __forceinline__ float wred_max(float v) {
#pragma unroll
  for (int o = 32; o; o >>= 1) v = fmaxf(v, __shfl_xor(v, o, 64));
  return v;
}

// ---------------- CSR build ----------------
__global__ void zero_int(int* __restrict__ p, int n) {
  int i = blockIdx.x * blockDim.x + threadIdx.x;
  if (i < n) p[i] = 0;
}

// edges e in [0, E0) come from edge_index; e in [E0, E0+N) are self-loops (node e-E0)
__global__ void hist_kernel(const int* __restrict__ ei, int* __restrict__ cnt, int E0, int N) {
  int e = blockIdx.x * blockDim.x + threadIdx.x;
  if (e >= E0 + N) return;
  int d = (e < E0) ? ei[E0 + e] : (e - E0);
  atomicAdd(&cnt[d], 1);
}

__global__ void scan1(const int* __restrict__ cnt, int* __restrict__ part, int N) {
  __shared__ int lds[256];
  int idx = blockIdx.x * 256 + threadIdx.x;
  int v = (idx < N) ? cnt[idx] : 0;
  lds[threadIdx.x] = v;
  __syncthreads();
  for (int o = 128; o; o >>= 1) {
    if (threadIdx.x < o) lds[threadIdx.x] += lds[threadIdx.x + o];
    __syncthreads();
  }
  if (threadIdx.x == 0) part[blockIdx.x] = lds[0];
}

__global__ void scan2(int* __restrict__ part, int nb, int* __restrict__ rp, int N, int E) {
  __shared__ int lds[256];
  int t = threadIdx.x;
  int v = (t < nb) ? part[t] : 0;
  lds[t] = v;
  __syncthreads();
  for (int o = 1; o < 256; o <<= 1) {
    int x = (t >= o) ? lds[t - o] : 0;
    __syncthreads();
    lds[t] += x;
    __syncthreads();
  }
  part[t] = lds[t] - v;  // exclusive
  if (t == 0) rp[N] = E;
}

__global__ void scan3(const int* __restrict__ cnt, const int* __restrict__ part,
                      int* __restrict__ rp, int N) {
  __shared__ int lds[256];
  int t = threadIdx.x;
  int idx = blockIdx.x * 256 + t;
  int v = (idx < N) ? cnt[idx] : 0;
  lds[t] = v;
  __syncthreads();
  for (int o = 1; o < 256; o <<= 1) {
    int x = (t >= o) ? lds[t - o] : 0;
    __syncthreads();
    lds[t] += x;
    __syncthreads();
  }
  if (idx < N) rp[idx] = part[blockIdx.x] + lds[t] - v;
}

__global__ void fill_kernel(const int* __restrict__ ei, const int* __restrict__ rp,
                            int* __restrict__ cnt, int* __restrict__ col, int E0, int N) {
  int e = blockIdx.x * blockDim.x + threadIdx.x;
  if (e >= E0 + N) return;
  int d, s;
  if (e < E0) { s = ei[e]; d = ei[E0 + e]; }
  else        { s = e - E0; d = s; }
  int pos = rp[d] + atomicAdd(&cnt[d], 1);
  col[pos] = s;
}

// ---------------- emb_w transpose: (C=64, F=128) -> [f][c] ----------------
__global__ void transpose_w(const float* __restrict__ w, float* __restrict__ wt, int F, int C) {
  int i = blockIdx.x * blockDim.x + threadIdx.x;
  if (i < F * C) {
    int f = i / C, c = i % C;
    wt[i] = w[c * F + f];
  }
}

// ---------------- fused GEMM + attention scores: lane=row, wave=c-chunk ----
// 256-thread blocks (4 waves). grid = (ceil(N/64), H). Block computes a
// 64-row x 64-col output tile for head h. Wave wv owns c-range
// [wv*16, wv*16+16): acc[16] per lane, lane = row. Weight addresses are
// wave-uniform -> s_load, and the per-wave weight stream is F*16*4 B (8 KB at
// F=128) -> fits the 16 KB scalar K$. x tile staged once per block in LDS
// (pad-65: bank = (lane+f)%32, 2-way aliasing = free), amortized over 4 waves.
// Scores si/sj: per-lane partials over 16 c, cross-wave sum via LDS.
template <int F, int H, bool SCORES, bool BIAS>
__global__ __launch_bounds__(256) void gemm_cs(
    const float* __restrict__ in, const float* __restrict__ w,
    const float* __restrict__ bias, const float* __restrict__ a,
    float* __restrict__ xh, float* __restrict__ si, float* __restrict__ sj,
    int nrows) {
  constexpr int PAD = 65;
  __shared__ float xl[64 * PAD];
  __shared__ float sred[2][4][64];
  const int tid = threadIdx.x;
  const int lane = tid & 63;
  const int wv = tid >> 6;
  const int h = blockIdx.y;
  const int n0 = blockIdx.x * 64;
  int n = n0 + lane;
  if (n >= nrows) n = nrows - 1;  // tail lanes duplicate row nrows-1 (benign)

  const float* __restrict__ wq = w + (size_t)h * F * 64 + wv * 16;

  float acc[16];
  if (BIAS) {
#pragma unroll
    for (int q = 0; q < 4; ++q) {
      const float4 bv = reinterpret_cast<const float4*>(bias + wv * 16)[q];  // uniform
      acc[q * 4 + 0] = bv.x; acc[q * 4 + 1] = bv.y;
      acc[q * 4 + 2] = bv.z; acc[q * 4 + 3] = bv.w;
    }
  } else {
#pragma unroll
    for (int c = 0; c < 16; ++c) acc[c] = 0.f;
  }

#pragma unroll
  for (int ch = 0; ch < F; ch += 64) {
    __syncthreads();
    // stage 64 rows x 64 f: 1024 float4 over 256 threads = 4 iters
#pragma unroll
    for (int it = 0; it < 4; ++it) {
      const int idx = it * 256 + tid;   // float4 index in tile
      const int row = idx >> 4;         // 16 float4 per row
      const int cq = idx & 15;
      int rg = n0 + row;
      if (rg >= nrows) rg = nrows - 1;
      const float4 v = *reinterpret_cast<const float4*>(in + (size_t)rg * F + ch + cq * 4);
      float* d = xl + row * PAD + cq * 4;
      d[0] = v.x; d[1] = v.y; d[2] = v.z; d[3] = v.w;
    }
    __syncthreads();

    const float* xr = xl + lane * PAD;
#pragma unroll 8
    for (int f = 0; f < 64; ++f) {
      const float xv = xr[f];
      const float4* wrow = reinterpret_cast<const float4*>(wq + (size_t)(ch + f) * 64);
#pragma unroll
      for (int q = 0; q < 4; ++q) {
        const float4 wvv = wrow[q];  // wave-uniform -> s_load
        acc[q * 4 + 0] = fmaf(xv, wvv.x, acc[q * 4 + 0]);
        acc[q * 4 + 1] = fmaf(xv, wvv.y, acc[q * 4 + 1]);
        acc[q * 4 + 2] = fmaf(xv, wvv.z, acc[q * 4 + 2]);
        acc[q * 4 + 3] = fmaf(xv, wvv.w, acc[q * 4 + 3]);
      }
    }
  }

  constexpr int HC = H * 64;
  float* orow = xh + (size_t)n * HC + h * 64 + wv * 16;
#pragma unroll
  for (int q = 0; q < 4; ++q) {
    float4 o;
    o.x = acc[q * 4 + 0]; o.y = acc[q * 4 + 1];
    o.z = acc[q * 4 + 2]; o.w = acc[q * 4 + 3];
    reinterpret_cast<float4*>(orow)[q] = o;
  }

  if (SCORES) {
    float vi = 0.f, vj = 0.f;
#pragma unroll
    for (int q = 0; q < 4; ++q) {
      const float4 av = reinterpret_cast<const float4*>(a + h * 128 + wv * 16)[q];       // uniform
      const float4 bv = reinterpret_cast<const float4*>(a + h * 128 + 64 + wv * 16)[q];  // uniform
      vi = fmaf(acc[q * 4 + 0], av.x, vi); vj = fmaf(acc[q * 4 + 0], bv.x, vj);
      vi = fmaf(acc[q * 4 + 1], av.y, vi); vj = fmaf(acc[q * 4 + 1], bv.y, vj);
      vi = fmaf(acc[q * 4 + 2], av.z, vi); vj = fmaf(acc[q * 4 + 2], bv.z, vj);
      vi = fmaf(acc[q * 4 + 3], av.w, vi); vj = fmaf(acc[q * 4 + 3], bv.w, vj);
    }
    sred[0][wv][lane] = vi;
    sred[1][wv][lane] = vj;
    __syncthreads();
    if (wv == 0) {
      const float vvi = sred[0][0][lane] + sred[0][1][lane] + sred[0][2][lane] + sred[0][3][lane];
      const float vvj = sred[1][0][lane] + sred[1][1][lane] + sred[1][2][lane] + sred[1][3][lane];
      si[(size_t)n * H + h] = vvi;
      sj[(size_t)n * H + h] = vvj;
    }
  }
}

// ---------------- per-(node,head) online-softmax aggregation ----------------
// One wave per (node, head). lane = feature c (0..63): gathers are 256 B
// coalesced rows. Edge loop: softmax chunk phase is edge-parallel across
// lanes; accumulation phase is unrolled by 8 (8 independent row loads in
// flight). out[n][h*64+c] = ELU(acc/denom).
template <int H>
__global__ __launch_bounds__(256) void agg_kernel(
    const float* __restrict__ xh, const float* __restrict__ si_g, const float* __restrict__ sj_g,
    const int* __restrict__ rp, const int* __restrict__ col,
    float* __restrict__ out, int N) {
  constexpr int HC = H * 64;
  const int lane = threadIdx.x & 63;
  const int wid = blockIdx.x * 4 + (threadIdx.x >> 6);
  if (wid >= N * H) return;
  const int n = (H == 2) ? (wid >> 1) : wid;
  const int h = (H == 2) ? (wid & 1) : 0;

  const int base = rp[n];
  const int deg = rp[n + 1] - base;

  const float siv = si_g[(size_t)n * H + h];
  float m = -INFINITY, den = 0.f, acc = 0.f;

  for (int start = 0; start < deg; start += 64) {
    const int k = start + lane;
    const bool vld = k < deg;
    const int s = vld ? col[base + k] : 0;
    float al = -INFINITY;
    if (vld) {
      const float t = siv + sj_g[(size_t)s * H + h];
      al = (t > 0.f) ? t : 0.2f * t;
    }
    // chunk max + online rescale
    const float nm = fmaxf(m, wred_max(al));
    const float r = __expf(m - nm);
    den *= r; acc *= r; m = nm;
    const float p = vld ? __expf(al - m) : 0.f;
    den += wred_sum(p);

    const int cc = min(64, deg - start);
    int kk = 0;
    for (; kk + 8 <= cc; kk += 8) {
      int ss[8]; float qq[8], vv[8];
#pragma unroll
      for (int u = 0; u < 8; ++u) {
        ss[u] = __shfl(s, kk + u, 64);
        qq[u] = __shfl(p, kk + u, 64);
      }
#pragma unroll
      for (int u = 0; u < 8; ++u) vv[u] = xh[(size_t)ss[u] * HC + h * 64 + lane];
#pragma unroll
      for (int u = 0; u < 8; ++u) acc = fmaf(qq[u], vv[u], acc);
    }
    for (; kk + 4 <= cc; kk += 4) {
      int ss[4]; float qq[4], vv[4];
#pragma unroll
      for (int u = 0; u < 4; ++u) {
        ss[u] = __shfl(s, kk + u, 64);
        qq[u] = __shfl(p, kk + u, 64);
      }
#pragma unroll
      for (int u = 0; u < 4; ++u) vv[u] = xh[(size_t)ss[u] * HC + h * 64 + lane];
#pragma unroll
      for (int u = 0; u < 4; ++u) acc = fmaf(qq[u], vv[u], acc);
    }
    for (; kk < cc; ++kk) {
      const int ss = __shfl(s, kk, 64);
      const float qq = __shfl(p, kk, 64);
      acc = fmaf(qq, xh[(size_t)ss * HC + h * 64 + lane], acc);
    }
  }

  float v = acc / (den + 1e-16f);
  v = (v > 0.f) ? v : expm1f(v);
  out[(size_t)n * HC + h * 64 + lane] = v;
}

// ---------------- launch ----------------
extern "C" void kernel_launch(void* const* d_in, const int* in_sizes, int n_in,
                              void* d_out, int out_size, void* d_ws, size_t ws_size,
                              hipStream_t stream) {
  const float* x     = (const float*)d_in[0];
  const int*   ei    = (const int*)d_in[1];
  const float* emb_w = (const float*)d_in[2];
  const float* emb_b = (const float*)d_in[3];
  const float* w0    = (const float*)d_in[4];
  const float* a0    = (const float*)d_in[5];
  const float* w1    = (const float*)d_in[6];
  const float* a1    = (const float*)d_in[7];
  const float* w2    = (const float*)d_in[8];
  const float* a2    = (const float*)d_in[9];

  const int IN_CH = 128;
  int N  = in_sizes[0] / IN_CH;   // 50000
  int E0 = in_sizes[1] / 2;       // 800000
  int E  = E0 + N;                // with self-loops

  // workspace carve (256B aligned)
  char* p = (char*)d_ws;
  auto alloc = [&](size_t bytes) -> char* {
    char* r = p;
    p += (bytes + 255) & ~(size_t)255;
    return r;
  };
  float* hA   = (float*)alloc((size_t)N * 128 * 4);
  float* hB   = (float*)alloc((size_t)N * 128 * 4);
  float* xh   = (float*)alloc((size_t)N * 128 * 4);
  float* si   = (float*)alloc((size_t)N * 2 * 4);
  float* sj   = (float*)alloc((size_t)N * 2 * 4);
  float* embT = (float*)alloc(128 * 64 * 4);
  int* rp   = (int*)alloc((size_t)(N + 1) * 4);
  int* cnt  = (int*)alloc((size_t)N * 4);
  int* col  = (int*)alloc((size_t)E * 4);
  int* part = (int*)alloc(1024);

  dim3 blk(256);
  int gN = (N + 255) / 256;     // 196
  int gE = (E + 255) / 256;

  // CSR build
  zero_int<<<gN, blk, 0, stream>>>(cnt, N);
  hist_kernel<<<gE, blk, 0, stream>>>(ei, cnt, E0, N);
  scan1<<<gN, blk, 0, stream>>>(cnt, part, N);
  scan2<<<1, blk, 0, stream>>>(part, gN, rp, N, E);
  scan3<<<gN, blk, 0, stream>>>(cnt, part, rp, N);
  zero_int<<<gN, blk, 0, stream>>>(cnt, N);
  fill_kernel<<<gE, blk, 0, stream>>>(ei, rp, cnt, col, E0, N);

  // embedding: h = x @ emb_w.T + emb_b   (transpose weights to [f][c] first)
  transpose_w<<<(128 * 64 + 255) / 256, blk, 0, stream>>>(emb_w, embT, 128, 64);

  int gR = (N + 63) / 64;  // 782 row-blocks
  gemm_cs<128, 1, false, true><<<dim3(gR, 1), blk, 0, stream>>>(x, embT, emb_b, nullptr, hA, nullptr, nullptr, N);

  // layer 0: F=64, H=2
  gemm_cs<64, 2, true, false><<<dim3(gR, 2), blk, 0, stream>>>(hA, w0, nullptr, a0, xh, si, sj, N);
  agg_kernel<2><<<(N * 2 + 3) / 4, blk, 0, stream>>>(xh, si, sj, rp, col, hB, N);

  // layer 1: F=128, H=2
  gemm_cs<128, 2, true, false><<<dim3(gR, 2), blk, 0, stream>>>(hB, w1, nullptr, a1, xh, si, sj, N);
  agg_kernel<2><<<(N * 2 + 3) / 4, blk, 0, stream>>>(xh, si, sj, rp, col, hA, N);

  // layer 2: F=128, H=1 -> output
  gemm_cs<128, 1, true, false><<<dim3(gR, 1), blk, 0, stream>>>(hA, w2, nullptr, a2, xh, si, sj, N);
  agg_kernel<1><<<(N + 3) / 4, blk, 0, stream>>>(xh, si, sj, rp, col, (float*)d_out, N);
}

// Round 6
// 296.415 us; speedup vs baseline: 1.9213x; 1.9213x over previous
//
#include <hip/hip_runtime.h>
#include <math.h>

typedef __attribute__((ext_vector_type(8))) short short8v;   // 8 bf16 (4 VGPR)
typedef __attribute__((ext_vector_type(4))) float float4v;   // MFMA C/D frag

union uf32 { unsigned int u; float f; };

__device__ __forceinline__ unsigned short f2b(float f) {  // fp32 -> bf16 RNE
  uf32 v; v.f = f;
  unsigned int u = v.u;
  return (unsigned short)((u + 0x7fffu + ((u >> 16) & 1u)) >> 16);
}
__device__ __forceinline__ float b2f(unsigned short b) {
  uf32 v; v.u = ((unsigned int)b) << 16;
  return v.f;
}

// ---------------- wave helpers ----------------
__device__ __forceinline__ float wred_sum(float v) {
#pragma unroll
  for (int o = 32; o; o >>= 1) v += __shfl_xor(v, o, 64);
  return v;
}
__device__ __forceinline__ float wred_max(float v) {
#pragma unroll
  for (int o = 32; o; o >>= 1) v = fmaxf(v, __shfl_xor(v, o, 64));
  return v;
}

// ---------------- CSR build ----------------
__global__ void zero_int(int* __restrict__ p, int n) {
  int i = blockIdx.x * blockDim.x + threadIdx.x;
  if (i < n) p[i] = 0;
}

__global__ void hist_kernel(const int* __restrict__ ei, int* __restrict__ cnt, int E0, int N) {
  int e = blockIdx.x * blockDim.x + threadIdx.x;
  if (e >= E0 + N) return;
  int d = (e < E0) ? ei[E0 + e] : (e - E0);
  atomicAdd(&cnt[d], 1);
}

__global__ void scan1(const int* __restrict__ cnt, int* __restrict__ part, int N) {
  __shared__ int lds[256];
  int idx = blockIdx.x * 256 + threadIdx.x;
  int v = (idx < N) ? cnt[idx] : 0;
  lds[threadIdx.x] = v;
  __syncthreads();
  for (int o = 128; o; o >>= 1) {
    if (threadIdx.x < o) lds[threadIdx.x] += lds[threadIdx.x + o];
    __syncthreads();
  }
  if (threadIdx.x == 0) part[blockIdx.x] = lds[0];
}

__global__ void scan2(int* __restrict__ part, int nb, int* __restrict__ rp, int N, int E) {
  __shared__ int lds[256];
  int t = threadIdx.x;
  int v = (t < nb) ? part[t] : 0;
  lds[t] = v;
  __syncthreads();
  for (int o = 1; o < 256; o <<= 1) {
    int x = (t >= o) ? lds[t - o] : 0;
    __syncthreads();
    lds[t] += x;
    __syncthreads();
  }
  part[t] = lds[t] - v;  // exclusive
  if (t == 0) rp[N] = E;
}

__global__ void scan3(const int* __restrict__ cnt, const int* __restrict__ part,
                      int* __restrict__ rp, int N) {
  __shared__ int lds[256];
  int t = threadIdx.x;
  int idx = blockIdx.x * 256 + t;
  int v = (idx < N) ? cnt[idx] : 0;
  lds[t] = v;
  __syncthreads();
  for (int o = 1; o < 256; o <<= 1) {
    int x = (t >= o) ? lds[t - o] : 0;
    __syncthreads();
    lds[t] += x;
    __syncthreads();
  }
  if (idx < N) rp[idx] = part[blockIdx.x] + lds[t] - v;
}

__global__ void fill_kernel(const int* __restrict__ ei, const int* __restrict__ rp,
                            int* __restrict__ cnt, int* __restrict__ col, int E0, int N) {
  int e = blockIdx.x * blockDim.x + threadIdx.x;
  if (e >= E0 + N) return;
  int d, s;
  if (e < E0) { s = ei[e]; d = ei[E0 + e]; }
  else        { s = e - E0; d = s; }
  int pos = rp[d] + atomicAdd(&cnt[d], 1);
  col[pos] = s;
}

// ---------------- weight pack: fp32 [h][f][c] (strided) -> bf16 MFMA B-frags
// Bpack element order: ((kk*4 + ct)*4 + g)*128 + col*8 + j
//   f = kk*32 + g*8 + j  (our chosen k-bijection, used identically for A)
//   c = ct*16 + col
__global__ void pack_w(const float* __restrict__ w, unsigned short* __restrict__ bp,
                       int F, int sf, int sc, int hstride) {
  int h = blockIdx.y;
  int i = blockIdx.x * 256 + threadIdx.x;
  if (i >= F * 64) return;
  int j = i & 7, colc = (i >> 3) & 15, g = (i >> 7) & 3, ct = (i >> 9) & 3, kk = i >> 11;
  int f = kk * 32 + g * 8 + j;
  int c = ct * 16 + colc;
  float v = w[(size_t)h * hstride + (size_t)f * sf + (size_t)c * sc];
  bp[(size_t)h * F * 64 + i] = f2b(v);
}

// ---------------- MFMA GEMM + attention scores ----------------
// Block: 256 threads (4 waves), 64-row x 64-col tile for head h = blockIdx.y.
// Wave wv: rows [wv*16, wv*16+16). A staged fp32->bf16 in LDS (pad +8 ushort).
// B-frags read from packed global (L2-hot). mfma_f32_16x16x32_bf16, fp32 acc.
// C/D: col = lane&15, row = (lane>>4)*4 + reg (m89-verified).
// Scores si/sj computed in fp32 from acc, 16-lane xor-reduce.
template <int F, int H, bool SCORES, bool BIAS, bool OBF>
__global__ __launch_bounds__(256) void gemm_mfma(
    const float* __restrict__ in, const unsigned short* __restrict__ bp,
    const float* __restrict__ bias, const float* __restrict__ a,
    void* __restrict__ xh_out, float* __restrict__ si, float* __restrict__ sj,
    int nrows) {
  constexpr int SA = F + 8;  // ushort stride, row base stays 16B aligned
  constexpr int NK = F / 32;
  constexpr int HC = H * 64;
  __shared__ __align__(16) unsigned short A_lds[64 * SA];

  const int tid = threadIdx.x;
  const int lane = tid & 63;
  const int wv = tid >> 6;
  const int h = blockIdx.y;
  const int n0 = blockIdx.x * 64;

  // stage A: 64 rows x F fp32 -> bf16 (coalesced float4 reads)
  {
    constexpr int NCH = 64 * F / 4;
#pragma unroll
    for (int i0 = 0; i0 < NCH; i0 += 256) {
      const int i = i0 + tid;
      const int row = i / (F / 4);
      const int c4 = i % (F / 4);
      int rg = n0 + row;
      if (rg >= nrows) rg = nrows - 1;
      const float4 v = *reinterpret_cast<const float4*>(in + (size_t)rg * F + c4 * 4);
      unsigned short* d = A_lds + row * SA + c4 * 4;
      d[0] = f2b(v.x); d[1] = f2b(v.y); d[2] = f2b(v.z); d[3] = f2b(v.w);
    }
  }
  __syncthreads();

  const int g = lane >> 4;
  const int cl = lane & 15;
  const unsigned short* __restrict__ bph = bp + (size_t)h * (NK * 4 * 4 * 128);

  float4v acc[4];
#pragma unroll
  for (int ct = 0; ct < 4; ++ct) acc[ct] = (float4v){0.f, 0.f, 0.f, 0.f};

  const unsigned short* ar = A_lds + (wv * 16 + cl) * SA + g * 8;
#pragma unroll
  for (int kk = 0; kk < NK; ++kk) {
    const short8v af = *reinterpret_cast<const short8v*>(ar + kk * 32);
#pragma unroll
    for (int ct = 0; ct < 4; ++ct) {
      const short8v bf = *reinterpret_cast<const short8v*>(
          bph + ((size_t)((kk * 4 + ct) * 4 + g)) * 128 + cl * 8);
      acc[ct] = __builtin_amdgcn_mfma_f32_16x16x32_bf16(af, bf, acc[ct], 0, 0, 0);
    }
  }

  if (BIAS) {
#pragma unroll
    for (int ct = 0; ct < 4; ++ct) {
      const float b = bias[ct * 16 + cl];
#pragma unroll
      for (int reg = 0; reg < 4; ++reg) acc[ct][reg] += b;
    }
  }

  // store: lane holds col = ct*16+cl, rows wv*16 + g*4 + reg
#pragma unroll
  for (int ct = 0; ct < 4; ++ct) {
    const int c = ct * 16 + cl;
#pragma unroll
    for (int reg = 0; reg < 4; ++reg) {
      const int n = n0 + wv * 16 + g * 4 + reg;
      if (n < nrows) {
        const size_t idx = (size_t)n * HC + h * 64 + c;
        if (OBF) ((unsigned short*)xh_out)[idx] = f2b(acc[ct][reg]);
        else     ((float*)xh_out)[idx] = acc[ct][reg];
      }
    }
  }

  if (SCORES) {
    float pi[4] = {0.f, 0.f, 0.f, 0.f}, pj[4] = {0.f, 0.f, 0.f, 0.f};
#pragma unroll
    for (int ct = 0; ct < 4; ++ct) {
      const float av = a[h * 128 + ct * 16 + cl];
      const float bv = a[h * 128 + 64 + ct * 16 + cl];
#pragma unroll
      for (int reg = 0; reg < 4; ++reg) {
        pi[reg] = fmaf(acc[ct][reg], av, pi[reg]);
        pj[reg] = fmaf(acc[ct][reg], bv, pj[reg]);
      }
    }
#pragma unroll
    for (int reg = 0; reg < 4; ++reg) {
#pragma unroll
      for (int o = 8; o; o >>= 1) {  // reduce across the 16-lane col group
        pi[reg] += __shfl_xor(pi[reg], o, 64);
        pj[reg] += __shfl_xor(pj[reg], o, 64);
      }
    }
    if (cl == 0) {
#pragma unroll
      for (int reg = 0; reg < 4; ++reg) {
        const int n = n0 + wv * 16 + g * 4 + reg;
        if (n < nrows) {
          si[(size_t)n * H + h] = pi[reg];
          sj[(size_t)n * H + h] = pj[reg];
        }
      }
    }
  }
}

// ---------------- per-(node,head) online-softmax aggregation (bf16 gather) ---
template <int H>
__global__ __launch_bounds__(256) void agg_kernel(
    const unsigned short* __restrict__ xh, const float* __restrict__ si_g,
    const float* __restrict__ sj_g, const int* __restrict__ rp,
    const int* __restrict__ col, float* __restrict__ out, int N) {
  constexpr int HC = H * 64;
  const int lane = threadIdx.x & 63;
  const int wid = blockIdx.x * 4 + (threadIdx.x >> 6);
  if (wid >= N * H) return;
  const int n = (H == 2) ? (wid >> 1) : wid;
  const int h = (H == 2) ? (wid & 1) : 0;

  const int base = rp[n];
  const int deg = rp[n + 1] - base;

  const float siv = si_g[(size_t)n * H + h];
  float m = -INFINITY, den = 0.f, acc = 0.f;

  for (int start = 0; start < deg; start += 64) {
    const int k = start + lane;
    const bool vld = k < deg;
    const int s = vld ? col[base + k] : 0;
    float al = -INFINITY;
    if (vld) {
      const float t = siv + sj_g[(size_t)s * H + h];
      al = (t > 0.f) ? t : 0.2f * t;
    }
    const float nm = fmaxf(m, wred_max(al));
    const float r = __expf(m - nm);
    den *= r; acc *= r; m = nm;
    const float p = vld ? __expf(al - m) : 0.f;
    den += wred_sum(p);

    const int cc = min(64, deg - start);
    int kk = 0;
    for (; kk + 8 <= cc; kk += 8) {
      int ss[8]; float qq[8], vv[8];
#pragma unroll
      for (int u = 0; u < 8; ++u) {
        ss[u] = __shfl(s, kk + u, 64);
        qq[u] = __shfl(p, kk + u, 64);
      }
#pragma unroll
      for (int u = 0; u < 8; ++u) vv[u] = b2f(xh[(size_t)ss[u] * HC + h * 64 + lane]);
#pragma unroll
      for (int u = 0; u < 8; ++u) acc = fmaf(qq[u], vv[u], acc);
    }
    for (; kk + 4 <= cc; kk += 4) {
      int ss[4]; float qq[4], vv[4];
#pragma unroll
      for (int u = 0; u < 4; ++u) {
        ss[u] = __shfl(s, kk + u, 64);
        qq[u] = __shfl(p, kk + u, 64);
      }
#pragma unroll
      for (int u = 0; u < 4; ++u) vv[u] = b2f(xh[(size_t)ss[u] * HC + h * 64 + lane]);
#pragma unroll
      for (int u = 0; u < 4; ++u) acc = fmaf(qq[u], vv[u], acc);
    }
    for (; kk < cc; ++kk) {
      const int ss = __shfl(s, kk, 64);
      const float qq = __shfl(p, kk, 64);
      acc = fmaf(qq, b2f(xh[(size_t)ss * HC + h * 64 + lane]), acc);
    }
  }

  float v = acc / (den + 1e-16f);
  v = (v > 0.f) ? v : expm1f(v);
  out[(size_t)n * HC + h * 64 + lane] = v;
}

// ---------------- launch ----------------
extern "C" void kernel_launch(void* const* d_in, const int* in_sizes, int n_in,
                              void* d_out, int out_size, void* d_ws, size_t ws_size,
                              hipStream_t stream) {
  const float* x     = (const float*)d_in[0];
  const int*   ei    = (const int*)d_in[1];
  const float* emb_w = (const float*)d_in[2];
  const float* emb_b = (const float*)d_in[3];
  const float* w0    = (const float*)d_in[4];
  const float* a0    = (const float*)d_in[5];
  const float* w1    = (const float*)d_in[6];
  const float* a1    = (const float*)d_in[7];
  const float* w2    = (const float*)d_in[8];
  const float* a2    = (const float*)d_in[9];

  const int IN_CH = 128;
  int N  = in_sizes[0] / IN_CH;   // 50000
  int E0 = in_sizes[1] / 2;       // 800000
  int E  = E0 + N;                // with self-loops

  // workspace carve (256B aligned)
  char* p = (char*)d_ws;
  auto alloc = [&](size_t bytes) -> char* {
    char* r = p;
    p += (bytes + 255) & ~(size_t)255;
    return r;
  };
  float* hA   = (float*)alloc((size_t)N * 128 * 4);
  float* hB   = (float*)alloc((size_t)N * 128 * 4);
  unsigned short* xhb = (unsigned short*)alloc((size_t)N * 128 * 2);
  float* si   = (float*)alloc((size_t)N * 2 * 4);
  float* sj   = (float*)alloc((size_t)N * 2 * 4);
  unsigned short* packE = (unsigned short*)alloc(128 * 64 * 2);
  unsigned short* pack0 = (unsigned short*)alloc(2 * 64 * 64 * 2);
  unsigned short* pack1 = (unsigned short*)alloc(2 * 128 * 64 * 2);
  unsigned short* pack2 = (unsigned short*)alloc(128 * 64 * 2);
  int* rp   = (int*)alloc((size_t)(N + 1) * 4);
  int* cnt  = (int*)alloc((size_t)N * 4);
  int* col  = (int*)alloc((size_t)E * 4);
  int* part = (int*)alloc(1024);

  dim3 blk(256);
  int gN = (N + 255) / 256;
  int gE = (E + 255) / 256;

  // CSR build
  zero_int<<<gN, blk, 0, stream>>>(cnt, N);
  hist_kernel<<<gE, blk, 0, stream>>>(ei, cnt, E0, N);
  scan1<<<gN, blk, 0, stream>>>(cnt, part, N);
  scan2<<<1, blk, 0, stream>>>(part, gN, rp, N, E);
  scan3<<<gN, blk, 0, stream>>>(cnt, part, rp, N);
  zero_int<<<gN, blk, 0, stream>>>(cnt, N);
  fill_kernel<<<gE, blk, 0, stream>>>(ei, rp, cnt, col, E0, N);

  // weight packs (bf16 fragment layout)
  pack_w<<<dim3(32, 1), blk, 0, stream>>>(emb_w, packE, 128, 1, 128, 0);       // transpose
  pack_w<<<dim3(16, 2), blk, 0, stream>>>(w0, pack0, 64, 64, 1, 64 * 64);
  pack_w<<<dim3(32, 2), blk, 0, stream>>>(w1, pack1, 128, 64, 1, 128 * 64);
  pack_w<<<dim3(32, 1), blk, 0, stream>>>(w2, pack2, 128, 64, 1, 0);

  int gR = (N + 63) / 64;  // 782

  // embedding: fp32 out (input to layer 0)
  gemm_mfma<128, 1, false, true, false><<<dim3(gR, 1), blk, 0, stream>>>(
      x, packE, emb_b, nullptr, hA, nullptr, nullptr, N);

  // layer 0: F=64, H=2 (bf16 xh + scores)
  gemm_mfma<64, 2, true, false, true><<<dim3(gR, 2), blk, 0, stream>>>(
      hA, pack0, nullptr, a0, xhb, si, sj, N);
  agg_kernel<2><<<(N * 2 + 3) / 4, blk, 0, stream>>>(xhb, si, sj, rp, col, hB, N);

  // layer 1: F=128, H=2
  gemm_mfma<128, 2, true, false, true><<<dim3(gR, 2), blk, 0, stream>>>(
      hB, pack1, nullptr, a1, xhb, si, sj, N);
  agg_kernel<2><<<(N * 2 + 3) / 4, blk, 0, stream>>>(xhb, si, sj, rp, col, hA, N);

  // layer 2: F=128, H=1 -> output
  gemm_mfma<128, 1, true, false, true><<<dim3(gR, 1), blk, 0, stream>>>(
      hA, pack2, nullptr, a2, xhb, si, sj, N);
  agg_kernel<1><<<(N + 3) / 4, blk, 0, stream>>>(xhb, si, sj, rp, col, (float*)d_out, N);
}

// Round 7
// 253.179 us; speedup vs baseline: 2.2494x; 1.1708x over previous
//
#include <hip/hip_runtime.h>
#include <math.h>

typedef __attribute__((ext_vector_type(8))) short short8v;   // 8 bf16 (4 VGPR)
typedef __attribute__((ext_vector_type(4))) float float4v;   // MFMA C/D frag

union uf32 { unsigned int u; float f; };

__device__ __forceinline__ unsigned short f2b(float f) {  // fp32 -> bf16 RNE
  uf32 v; v.f = f;
  unsigned int u = v.u;
  return (unsigned short)((u + 0x7fffu + ((u >> 16) & 1u)) >> 16);
}

// ---------------- CSR build ----------------
__global__ void zero_int(int* __restrict__ p, int n) {
  int i = blockIdx.x * blockDim.x + threadIdx.x;
  if (i < n) p[i] = 0;
}

__global__ void hist_kernel(const int* __restrict__ ei, int* __restrict__ cnt, int E0, int N) {
  int e = blockIdx.x * blockDim.x + threadIdx.x;
  if (e >= E0 + N) return;
  int d = (e < E0) ? ei[E0 + e] : (e - E0);
  atomicAdd(&cnt[d], 1);
}

__global__ void scan1(const int* __restrict__ cnt, int* __restrict__ part, int N) {
  __shared__ int lds[256];
  int idx = blockIdx.x * 256 + threadIdx.x;
  int v = (idx < N) ? cnt[idx] : 0;
  lds[threadIdx.x] = v;
  __syncthreads();
  for (int o = 128; o; o >>= 1) {
    if (threadIdx.x < o) lds[threadIdx.x] += lds[threadIdx.x + o];
    __syncthreads();
  }
  if (threadIdx.x == 0) part[blockIdx.x] = lds[0];
}

__global__ void scan2(int* __restrict__ part, int nb, int* __restrict__ rp, int N, int E) {
  __shared__ int lds[256];
  int t = threadIdx.x;
  int v = (t < nb) ? part[t] : 0;
  lds[t] = v;
  __syncthreads();
  for (int o = 1; o < 256; o <<= 1) {
    int x = (t >= o) ? lds[t - o] : 0;
    __syncthreads();
    lds[t] += x;
    __syncthreads();
  }
  part[t] = lds[t] - v;  // exclusive
  if (t == 0) rp[N] = E;
}

__global__ void scan3(const int* __restrict__ cnt, const int* __restrict__ part,
                      int* __restrict__ rp, int N) {
  __shared__ int lds[256];
  int t = threadIdx.x;
  int idx = blockIdx.x * 256 + t;
  int v = (idx < N) ? cnt[idx] : 0;
  lds[t] = v;
  __syncthreads();
  for (int o = 1; o < 256; o <<= 1) {
    int x = (t >= o) ? lds[t - o] : 0;
    __syncthreads();
    lds[t] += x;
    __syncthreads();
  }
  if (idx < N) rp[idx] = part[blockIdx.x] + lds[t] - v;
}

__global__ void fill_kernel(const int* __restrict__ ei, const int* __restrict__ rp,
                            int* __restrict__ cnt, int* __restrict__ col, int E0, int N) {
  int e = blockIdx.x * blockDim.x + threadIdx.x;
  if (e >= E0 + N) return;
  int d, s;
  if (e < E0) { s = ei[e]; d = ei[E0 + e]; }
  else        { s = e - E0; d = s; }
  int pos = rp[d] + atomicAdd(&cnt[d], 1);
  col[pos] = s;
}

// ---------------- weight pack: fp32 [h][f][c] (strided) -> bf16 MFMA B-frags
__global__ void pack_w(const float* __restrict__ w, unsigned short* __restrict__ bp,
                       int F, int sf, int sc, int hstride) {
  int h = blockIdx.y;
  int i = blockIdx.x * 256 + threadIdx.x;
  if (i >= F * 64) return;
  int j = i & 7, colc = (i >> 3) & 15, g = (i >> 7) & 3, ct = (i >> 9) & 3, kk = i >> 11;
  int f = kk * 32 + g * 8 + j;
  int c = ct * 16 + colc;
  float v = w[(size_t)h * hstride + (size_t)f * sf + (size_t)c * sc];
  bp[(size_t)h * F * 64 + i] = f2b(v);
}

// ---------------- MFMA GEMM + attention scores ----------------
template <int F, int H, bool SCORES, bool BIAS, bool OBF>
__global__ __launch_bounds__(256) void gemm_mfma(
    const float* __restrict__ in, const unsigned short* __restrict__ bp,
    const float* __restrict__ bias, const float* __restrict__ a,
    void* __restrict__ xh_out, float* __restrict__ si, float* __restrict__ sj,
    int nrows) {
  constexpr int SA = F + 8;  // ushort stride, row base stays 16B aligned
  constexpr int NK = F / 32;
  constexpr int HC = H * 64;
  __shared__ __align__(16) unsigned short A_lds[64 * SA];

  const int tid = threadIdx.x;
  const int lane = tid & 63;
  const int wv = tid >> 6;
  const int h = blockIdx.y;
  const int n0 = blockIdx.x * 64;

  // stage A: 64 rows x F fp32 -> bf16 (coalesced float4 reads)
  {
    constexpr int NCH = 64 * F / 4;
#pragma unroll
    for (int i0 = 0; i0 < NCH; i0 += 256) {
      const int i = i0 + tid;
      const int row = i / (F / 4);
      const int c4 = i % (F / 4);
      int rg = n0 + row;
      if (rg >= nrows) rg = nrows - 1;
      const float4 v = *reinterpret_cast<const float4*>(in + (size_t)rg * F + c4 * 4);
      unsigned short* d = A_lds + row * SA + c4 * 4;
      d[0] = f2b(v.x); d[1] = f2b(v.y); d[2] = f2b(v.z); d[3] = f2b(v.w);
    }
  }
  __syncthreads();

  const int g = lane >> 4;
  const int cl = lane & 15;
  const unsigned short* __restrict__ bph = bp + (size_t)h * (NK * 4 * 4 * 128);

  float4v acc[4];
#pragma unroll
  for (int ct = 0; ct < 4; ++ct) acc[ct] = (float4v){0.f, 0.f, 0.f, 0.f};

  const unsigned short* ar = A_lds + (wv * 16 + cl) * SA + g * 8;
#pragma unroll
  for (int kk = 0; kk < NK; ++kk) {
    const short8v af = *reinterpret_cast<const short8v*>(ar + kk * 32);
#pragma unroll
    for (int ct = 0; ct < 4; ++ct) {
      const short8v bf = *reinterpret_cast<const short8v*>(
          bph + ((size_t)((kk * 4 + ct) * 4 + g)) * 128 + cl * 8);
      acc[ct] = __builtin_amdgcn_mfma_f32_16x16x32_bf16(af, bf, acc[ct], 0, 0, 0);
    }
  }

  if (BIAS) {
#pragma unroll
    for (int ct = 0; ct < 4; ++ct) {
      const float b = bias[ct * 16 + cl];
#pragma unroll
      for (int reg = 0; reg < 4; ++reg) acc[ct][reg] += b;
    }
  }

  // store: lane holds col = ct*16+cl, rows wv*16 + g*4 + reg
#pragma unroll
  for (int ct = 0; ct < 4; ++ct) {
    const int c = ct * 16 + cl;
#pragma unroll
    for (int reg = 0; reg < 4; ++reg) {
      const int n = n0 + wv * 16 + g * 4 + reg;
      if (n < nrows) {
        const size_t idx = (size_t)n * HC + h * 64 + c;
        if (OBF) ((unsigned short*)xh_out)[idx] = f2b(acc[ct][reg]);
        else     ((float*)xh_out)[idx] = acc[ct][reg];
      }
    }
  }

  if (SCORES) {
    float pi[4] = {0.f, 0.f, 0.f, 0.f}, pj[4] = {0.f, 0.f, 0.f, 0.f};
#pragma unroll
    for (int ct = 0; ct < 4; ++ct) {
      const float av = a[h * 128 + ct * 16 + cl];
      const float bv = a[h * 128 + 64 + ct * 16 + cl];
#pragma unroll
      for (int reg = 0; reg < 4; ++reg) {
        pi[reg] = fmaf(acc[ct][reg], av, pi[reg]);
        pj[reg] = fmaf(acc[ct][reg], bv, pj[reg]);
      }
    }
#pragma unroll
    for (int reg = 0; reg < 4; ++reg) {
#pragma unroll
      for (int o = 8; o; o >>= 1) {  // reduce across the 16-lane col group
        pi[reg] += __shfl_xor(pi[reg], o, 64);
        pj[reg] += __shfl_xor(pj[reg], o, 64);
      }
    }
    if (cl == 0) {
#pragma unroll
      for (int reg = 0; reg < 4; ++reg) {
        const int n = n0 + wv * 16 + g * 4 + reg;
        if (n < nrows) {
          si[(size_t)n * H + h] = pi[reg];
          sj[(size_t)n * H + h] = pj[reg];
        }
      }
    }
  }
}

// ---------------- per-node online-softmax aggregation (both heads / wave) ----
// One wave per node, 32-edge chunks.
// H==2: lane half = head (lanes 0-31 -> h0, 32-63 -> h1). Lane el=lane&31 owns
//   edge el of the chunk for its head. Gather: lane loads uint (2 bf16) at
//   xhb[s*128 + lane*4B] -> one fully-coalesced 256 B row read per edge.
// H==1: halves process TWO edges per iteration (lane<32 -> edge kk, else kk+1),
//   each lane loads uint = 2 features of its edge's 128 B row; final
//   shfl_xor(32) combines the half-sums.
// Softmax reductions: 5-step shfl_xor (16..1) = per-half (= per-head) reduce.
template <int H>
__global__ __launch_bounds__(256) void agg_kernel(
    const unsigned short* __restrict__ xh, const float* __restrict__ si_g,
    const float* __restrict__ sj_g, const int* __restrict__ rp,
    const int* __restrict__ col, float* __restrict__ out, int N) {
  constexpr int HC = H * 64;
  const int lane = threadIdx.x & 63;
  const int n = blockIdx.x * 4 + (threadIdx.x >> 6);
  if (n >= N) return;
  const int el = lane & 31;
  const int hl = (H == 2) ? (lane >> 5) : 0;

  const int base = rp[n];
  const int deg = rp[n + 1] - base;
  const float siv = si_g[(size_t)n * H + hl];

  const int soff = (H == 1) ? (lane >> 5) : 0;          // edge-pair offset (H=1)
  const int qoff = (H == 1) ? (lane >> 5) : (lane & 32);
  constexpr int STEP = (H == 2) ? 1 : 2;
  const unsigned int loff = (H == 2) ? (unsigned)lane * 2 : (unsigned)el * 2;

  float m = -INFINITY, den = 0.f, acc0 = 0.f, acc1 = 0.f;

  for (int start = 0; start < deg; start += 32) {
    const int k = start + el;
    const bool vld = k < deg;
    const int s = vld ? col[base + k] : 0;
    float al = -INFINITY;
    if (vld) {
      const float t = siv + sj_g[(size_t)s * H + hl];
      al = (t > 0.f) ? t : 0.2f * t;
    }
    // per-half (per-head) chunk max
    float cm = al;
#pragma unroll
    for (int o = 16; o; o >>= 1) cm = fmaxf(cm, __shfl_xor(cm, o, 64));
    const float nm = fmaxf(m, cm);
    const float r = __expf(m - nm);
    den *= r; acc0 *= r; acc1 *= r; m = nm;
    const float p = vld ? __expf(al - m) : 0.f;
    float ps = p;
#pragma unroll
    for (int o = 16; o; o >>= 1) ps += __shfl_xor(ps, o, 64);
    den += ps;

    const int cc = min(32, deg - start);
    int kk = 0;
    for (; kk + 4 * STEP <= cc; kk += 4 * STEP) {
      int sb[4]; float qb[4]; unsigned int uv[4];
#pragma unroll
      for (int u = 0; u < 4; ++u) {
        const int e = kk + u * STEP;
        sb[u] = __shfl(s, e + soff, 64);
        qb[u] = __shfl(p, e + qoff, 64);
      }
#pragma unroll
      for (int u = 0; u < 4; ++u)
        uv[u] = *reinterpret_cast<const unsigned int*>(xh + (size_t)sb[u] * HC + loff);
#pragma unroll
      for (int u = 0; u < 4; ++u) {
        uf32 lo, hi;
        lo.u = uv[u] << 16;
        hi.u = uv[u] & 0xffff0000u;
        acc0 = fmaf(qb[u], lo.f, acc0);
        acc1 = fmaf(qb[u], hi.f, acc1);
      }
    }
    for (; kk < cc; kk += STEP) {
      const int sb = __shfl(s, kk + soff, 64);
      const float qb = __shfl(p, kk + qoff, 64);
      const unsigned int uv = *reinterpret_cast<const unsigned int*>(xh + (size_t)sb * HC + loff);
      uf32 lo, hi;
      lo.u = uv << 16;
      hi.u = uv & 0xffff0000u;
      acc0 = fmaf(qb, lo.f, acc0);
      acc1 = fmaf(qb, hi.f, acc1);
    }
  }

  if (H == 2) {
    const float invd = 1.f / (den + 1e-16f);
    float v0 = acc0 * invd, v1 = acc1 * invd;
    v0 = (v0 > 0.f) ? v0 : expm1f(v0);
    v1 = (v1 > 0.f) ? v1 : expm1f(v1);
    float2 o; o.x = v0; o.y = v1;
    *reinterpret_cast<float2*>(out + (size_t)n * 128 + lane * 2) = o;
  } else {
    acc0 += __shfl_xor(acc0, 32, 64);
    acc1 += __shfl_xor(acc1, 32, 64);
    if (lane < 32) {
      const float invd = 1.f / (den + 1e-16f);
      float v0 = acc0 * invd, v1 = acc1 * invd;
      v0 = (v0 > 0.f) ? v0 : expm1f(v0);
      v1 = (v1 > 0.f) ? v1 : expm1f(v1);
      float2 o; o.x = v0; o.y = v1;
      *reinterpret_cast<float2*>(out + (size_t)n * 64 + el * 2) = o;
    }
  }
}

// ---------------- launch ----------------
extern "C" void kernel_launch(void* const* d_in, const int* in_sizes, int n_in,
                              void* d_out, int out_size, void* d_ws, size_t ws_size,
                              hipStream_t stream) {
  const float* x     = (const float*)d_in[0];
  const int*   ei    = (const int*)d_in[1];
  const float* emb_w = (const float*)d_in[2];
  const float* emb_b = (const float*)d_in[3];
  const float* w0    = (const float*)d_in[4];
  const float* a0    = (const float*)d_in[5];
  const float* w1    = (const float*)d_in[6];
  const float* a1    = (const float*)d_in[7];
  const float* w2    = (const float*)d_in[8];
  const float* a2    = (const float*)d_in[9];

  const int IN_CH = 128;
  int N  = in_sizes[0] / IN_CH;   // 50000
  int E0 = in_sizes[1] / 2;       // 800000
  int E  = E0 + N;                // with self-loops

  // workspace carve (256B aligned)
  char* p = (char*)d_ws;
  auto alloc = [&](size_t bytes) -> char* {
    char* r = p;
    p += (bytes + 255) & ~(size_t)255;
    return r;
  };
  float* hA   = (float*)alloc((size_t)N * 128 * 4);
  float* hB   = (float*)alloc((size_t)N * 128 * 4);
  unsigned short* xhb = (unsigned short*)alloc((size_t)N * 128 * 2);
  float* si   = (float*)alloc((size_t)N * 2 * 4);
  float* sj   = (float*)alloc((size_t)N * 2 * 4);
  unsigned short* packE = (unsigned short*)alloc(128 * 64 * 2);
  unsigned short* pack0 = (unsigned short*)alloc(2 * 64 * 64 * 2);
  unsigned short* pack1 = (unsigned short*)alloc(2 * 128 * 64 * 2);
  unsigned short* pack2 = (unsigned short*)alloc(128 * 64 * 2);
  int* rp   = (int*)alloc((size_t)(N + 1) * 4);
  int* cnt  = (int*)alloc((size_t)N * 4);
  int* col  = (int*)alloc((size_t)E * 4);
  int* part = (int*)alloc(1024);

  dim3 blk(256);
  int gN = (N + 255) / 256;
  int gE = (E + 255) / 256;

  // CSR build
  zero_int<<<gN, blk, 0, stream>>>(cnt, N);
  hist_kernel<<<gE, blk, 0, stream>>>(ei, cnt, E0, N);
  scan1<<<gN, blk, 0, stream>>>(cnt, part, N);
  scan2<<<1, blk, 0, stream>>>(part, gN, rp, N, E);
  scan3<<<gN, blk, 0, stream>>>(cnt, part, rp, N);
  zero_int<<<gN, blk, 0, stream>>>(cnt, N);
  fill_kernel<<<gE, blk, 0, stream>>>(ei, rp, cnt, col, E0, N);

  // weight packs (bf16 fragment layout)
  pack_w<<<dim3(32, 1), blk, 0, stream>>>(emb_w, packE, 128, 1, 128, 0);       // transpose
  pack_w<<<dim3(16, 2), blk, 0, stream>>>(w0, pack0, 64, 64, 1, 64 * 64);
  pack_w<<<dim3(32, 2), blk, 0, stream>>>(w1, pack1, 128, 64, 1, 128 * 64);
  pack_w<<<dim3(32, 1), blk, 0, stream>>>(w2, pack2, 128, 64, 1, 0);

  int gR = (N + 63) / 64;  // 782

  // embedding: fp32 out (input to layer 0)
  gemm_mfma<128, 1, false, true, false><<<dim3(gR, 1), blk, 0, stream>>>(
      x, packE, emb_b, nullptr, hA, nullptr, nullptr, N);

  // layer 0: F=64, H=2 (bf16 xh + scores)
  gemm_mfma<64, 2, true, false, true><<<dim3(gR, 2), blk, 0, stream>>>(
      hA, pack0, nullptr, a0, xhb, si, sj, N);
  agg_kernel<2><<<(N + 3) / 4, blk, 0, stream>>>(xhb, si, sj, rp, col, hB, N);

  // layer 1: F=128, H=2
  gemm_mfma<128, 2, true, false, true><<<dim3(gR, 2), blk, 0, stream>>>(
      hB, pack1, nullptr, a1, xhb, si, sj, N);
  agg_kernel<2><<<(N + 3) / 4, blk, 0, stream>>>(xhb, si, sj, rp, col, hA, N);

  // layer 2: F=128, H=1 -> output
  gemm_mfma<128, 1, true, false, true><<<dim3(gR, 1), blk, 0, stream>>>(
      hA, pack2, nullptr, a2, xhb, si, sj, N);
  agg_kernel<1><<<(N + 3) / 4, blk, 0, stream>>>(xhb, si, sj, rp, col, (float*)d_out, N);
}

// Round 8
// 215.561 us; speedup vs baseline: 2.6419x; 1.1745x over previous
//
#include <hip/hip_runtime.h>
#include <math.h>

typedef __attribute__((ext_vector_type(8))) short short8v;   // 8 bf16 (4 VGPR)
typedef __attribute__((ext_vector_type(4))) float float4v;   // MFMA C/D frag

union uf32 { unsigned int u; float f; };

__device__ __forceinline__ unsigned short f2b(float f) {  // fp32 -> bf16 RNE
  uf32 v; v.f = f;
  unsigned int u = v.u;
  return (unsigned short)((u + 0x7fffu + ((u >> 16) & 1u)) >> 16);
}

// ================= CSR build (XCD-local atomics, atomic-free scatter) =======
__global__ void zero8(int* __restrict__ p, int n) {
  int i = blockIdx.x * 256 + threadIdx.x;
  if (i < n) p[i] = 0;
}

// Per-virtual-XCD histogram; records each edge's local position (removes the
// atomic from the fill pass). vx = blockIdx.x & 7 matches the default
// round-robin block->XCD mapping, so atomics on cnt8[vx] stay XCD-local.
__global__ void hist8(const int* __restrict__ ei, int* __restrict__ cnt8,
                      unsigned short* __restrict__ lpos, int E0, int N) {
  int e = blockIdx.x * 256 + threadIdx.x;
  if (e >= E0 + N) return;
  int vx = blockIdx.x & 7;
  int d = (e < E0) ? ei[E0 + e] : (e - E0);
  lpos[e] = (unsigned short)atomicAdd(&cnt8[vx * N + d], 1);
}

// Fold per-XCD counts -> total degree + per-XCD exclusive base; fused
// block-reduction of degrees into part[] (replaces old scan1).
__global__ void fold8(const int* __restrict__ cnt8, int* __restrict__ base8,
                      int* __restrict__ cnt, int* __restrict__ part, int N) {
  __shared__ int lds[256];
  int d = blockIdx.x * 256 + threadIdx.x;
  int run = 0;
  if (d < N) {
#pragma unroll
    for (int x = 0; x < 8; ++x) {
      int t = cnt8[x * N + d];
      base8[x * N + d] = run;
      run += t;
    }
    cnt[d] = run;
  }
  lds[threadIdx.x] = (d < N) ? run : 0;
  __syncthreads();
  for (int o = 128; o; o >>= 1) {
    if (threadIdx.x < o) lds[threadIdx.x] += lds[threadIdx.x + o];
    __syncthreads();
  }
  if (threadIdx.x == 0) part[blockIdx.x] = lds[0];
}

// single-block exclusive scan with carry (handles any nb)
__global__ void scan_carry(int* __restrict__ part, int nb) {
  __shared__ int lds[256];
  __shared__ int carry;
  if (threadIdx.x == 0) carry = 0;
  __syncthreads();
  for (int t0 = 0; t0 < nb; t0 += 256) {
    int t = t0 + threadIdx.x;
    int v = (t < nb) ? part[t] : 0;
    lds[threadIdx.x] = v;
    __syncthreads();
    for (int o = 1; o < 256; o <<= 1) {
      int x = (threadIdx.x >= o) ? lds[threadIdx.x - o] : 0;
      __syncthreads();
      lds[threadIdx.x] += x;
      __syncthreads();
    }
    if (t < nb) part[t] = carry + lds[threadIdx.x] - v;  // exclusive
    __syncthreads();
    if (threadIdx.x == 255) carry += lds[255];
    __syncthreads();
  }
}

__global__ void scan3(const int* __restrict__ cnt, const int* __restrict__ part,
                      int* __restrict__ rp, int N, int E) {
  __shared__ int lds[256];
  int t = threadIdx.x;
  int idx = blockIdx.x * 256 + t;
  int v = (idx < N) ? cnt[idx] : 0;
  lds[t] = v;
  __syncthreads();
  for (int o = 1; o < 256; o <<= 1) {
    int x = (t >= o) ? lds[t - o] : 0;
    __syncthreads();
    lds[t] += x;
    __syncthreads();
  }
  if (idx < N) rp[idx] = part[blockIdx.x] + lds[t] - v;
  if (blockIdx.x == 0 && t == 0) rp[N] = E;
}

// rb8[x][d] = rp[d] + base8[x][d]  (one random read per edge in fillx)
__global__ void addrp(const int* __restrict__ rp, const int* __restrict__ base8,
                      int* __restrict__ rb8, int N) {
  int d = blockIdx.x * 256 + threadIdx.x;
  int x = blockIdx.y;
  if (d < N) rb8[x * N + d] = rp[d] + base8[x * N + d];
}

// atomic-free scatter: same grid/vx mapping as hist8
__global__ void fillx(const int* __restrict__ ei, const int* __restrict__ rb8,
                      const unsigned short* __restrict__ lpos,
                      int* __restrict__ col, int E0, int N) {
  int e = blockIdx.x * 256 + threadIdx.x;
  if (e >= E0 + N) return;
  int vx = blockIdx.x & 7;
  int s, d;
  if (e < E0) { s = ei[e]; d = ei[E0 + e]; }
  else        { s = e - E0; d = s; }
  col[rb8[vx * N + d] + lpos[e]] = s;
}

// ---------------- weight pack: fp32 [h][f][c] (strided) -> bf16 MFMA B-frags
__global__ void pack_w(const float* __restrict__ w, unsigned short* __restrict__ bp,
                       int F, int sf, int sc, int hstride) {
  int h = blockIdx.y;
  int i = blockIdx.x * 256 + threadIdx.x;
  if (i >= F * 64) return;
  int j = i & 7, colc = (i >> 3) & 15, g = (i >> 7) & 3, ct = (i >> 9) & 3, kk = i >> 11;
  int f = kk * 32 + g * 8 + j;
  int c = ct * 16 + colc;
  float v = w[(size_t)h * hstride + (size_t)f * sf + (size_t)c * sc];
  bp[(size_t)h * F * 64 + i] = f2b(v);
}

// ---------------- MFMA GEMM + attention scores ----------------
// Block: 256 threads (4 waves), 64x64 tile, head h = blockIdx.y.
// A staged in LDS (bf16 copy if IBF, fp32->bf16 convert otherwise).
// B-frags from packed global (L2-hot). mfma_f32_16x16x32_bf16, fp32 acc.
template <int F, int H, bool SCORES, bool BIAS, bool IBF, bool OBF>
__global__ __launch_bounds__(256) void gemm_mfma(
    const void* __restrict__ in, const unsigned short* __restrict__ bp,
    const float* __restrict__ bias, const float* __restrict__ a,
    void* __restrict__ xh_out, float* __restrict__ si, float* __restrict__ sj,
    int nrows) {
  constexpr int SA = F + 8;  // ushort stride, row base stays 16B aligned
  constexpr int NK = F / 32;
  constexpr int HC = H * 64;
  __shared__ __align__(16) unsigned short A_lds[64 * SA];

  const int tid = threadIdx.x;
  const int lane = tid & 63;
  const int wv = tid >> 6;
  const int h = blockIdx.y;
  const int n0 = blockIdx.x * 64;

  if (IBF) {  // bf16 input: straight ushort8 copies
    const unsigned short* inb = (const unsigned short*)in;
    constexpr int NCH = 64 * F / 8;
#pragma unroll
    for (int i0 = 0; i0 < NCH; i0 += 256) {
      const int i = i0 + tid;
      const int row = i / (F / 8);
      const int c8 = i % (F / 8);
      int rg = n0 + row;
      if (rg >= nrows) rg = nrows - 1;
      const short8v v = *reinterpret_cast<const short8v*>(inb + (size_t)rg * F + c8 * 8);
      *reinterpret_cast<short8v*>(A_lds + row * SA + c8 * 8) = v;
    }
  } else {    // fp32 input: convert while staging
    const float* inf = (const float*)in;
    constexpr int NCH = 64 * F / 4;
#pragma unroll
    for (int i0 = 0; i0 < NCH; i0 += 256) {
      const int i = i0 + tid;
      const int row = i / (F / 4);
      const int c4 = i % (F / 4);
      int rg = n0 + row;
      if (rg >= nrows) rg = nrows - 1;
      const float4 v = *reinterpret_cast<const float4*>(inf + (size_t)rg * F + c4 * 4);
      unsigned short* d = A_lds + row * SA + c4 * 4;
      d[0] = f2b(v.x); d[1] = f2b(v.y); d[2] = f2b(v.z); d[3] = f2b(v.w);
    }
  }
  __syncthreads();

  const int g = lane >> 4;
  const int cl = lane & 15;
  const unsigned short* __restrict__ bph = bp + (size_t)h * (NK * 4 * 4 * 128);

  float4v acc[4];
#pragma unroll
  for (int ct = 0; ct < 4; ++ct) acc[ct] = (float4v){0.f, 0.f, 0.f, 0.f};

  const unsigned short* ar = A_lds + (wv * 16 + cl) * SA + g * 8;
#pragma unroll
  for (int kk = 0; kk < NK; ++kk) {
    const short8v af = *reinterpret_cast<const short8v*>(ar + kk * 32);
#pragma unroll
    for (int ct = 0; ct < 4; ++ct) {
      const short8v bf = *reinterpret_cast<const short8v*>(
          bph + ((size_t)((kk * 4 + ct) * 4 + g)) * 128 + cl * 8);
      acc[ct] = __builtin_amdgcn_mfma_f32_16x16x32_bf16(af, bf, acc[ct], 0, 0, 0);
    }
  }

  if (BIAS) {
#pragma unroll
    for (int ct = 0; ct < 4; ++ct) {
      const float b = bias[ct * 16 + cl];
#pragma unroll
      for (int reg = 0; reg < 4; ++reg) acc[ct][reg] += b;
    }
  }

  // store: lane holds col = ct*16+cl, rows wv*16 + g*4 + reg
#pragma unroll
  for (int ct = 0; ct < 4; ++ct) {
    const int c = ct * 16 + cl;
#pragma unroll
    for (int reg = 0; reg < 4; ++reg) {
      const int n = n0 + wv * 16 + g * 4 + reg;
      if (n < nrows) {
        const size_t idx = (size_t)n * HC + h * 64 + c;
        if (OBF) ((unsigned short*)xh_out)[idx] = f2b(acc[ct][reg]);
        else     ((float*)xh_out)[idx] = acc[ct][reg];
      }
    }
  }

  if (SCORES) {
    float pi[4] = {0.f, 0.f, 0.f, 0.f}, pj[4] = {0.f, 0.f, 0.f, 0.f};
#pragma unroll
    for (int ct = 0; ct < 4; ++ct) {
      const float av = a[h * 128 + ct * 16 + cl];
      const float bv = a[h * 128 + 64 + ct * 16 + cl];
#pragma unroll
      for (int reg = 0; reg < 4; ++reg) {
        pi[reg] = fmaf(acc[ct][reg], av, pi[reg]);
        pj[reg] = fmaf(acc[ct][reg], bv, pj[reg]);
      }
    }
#pragma unroll
    for (int reg = 0; reg < 4; ++reg) {
#pragma unroll
      for (int o = 8; o; o >>= 1) {  // reduce across the 16-lane col group
        pi[reg] += __shfl_xor(pi[reg], o, 64);
        pj[reg] += __shfl_xor(pj[reg], o, 64);
      }
    }
    if (cl == 0) {
#pragma unroll
      for (int reg = 0; reg < 4; ++reg) {
        const int n = n0 + wv * 16 + g * 4 + reg;
        if (n < nrows) {
          si[(size_t)n * H + h] = pi[reg];
          sj[(size_t)n * H + h] = pj[reg];
        }
      }
    }
  }
}

// ---------------- per-node online-softmax aggregation (both heads / wave) ----
// One wave per node, 32-edge chunks. H==2: lane half = head; lane loads uint
// (2 bf16) -> one coalesced 256 B row read per edge. H==1: halves process two
// edges per iteration; final shfl_xor(32) combine. OBF: write bf16 output.
template <int H, bool OBF>
__global__ __launch_bounds__(256) void agg_kernel(
    const unsigned short* __restrict__ xh, const float* __restrict__ si_g,
    const float* __restrict__ sj_g, const int* __restrict__ rp,
    const int* __restrict__ col, void* __restrict__ out, int N) {
  constexpr int HC = H * 64;
  const int lane = threadIdx.x & 63;
  const int n = blockIdx.x * 4 + (threadIdx.x >> 6);
  if (n >= N) return;
  const int el = lane & 31;
  const int hl = (H == 2) ? (lane >> 5) : 0;

  const int base = rp[n];
  const int deg = rp[n + 1] - base;
  const float siv = si_g[(size_t)n * H + hl];

  const int soff = (H == 1) ? (lane >> 5) : 0;
  const int qoff = (H == 1) ? (lane >> 5) : (lane & 32);
  constexpr int STEP = (H == 2) ? 1 : 2;
  const unsigned int loff = (H == 2) ? (unsigned)lane * 2 : (unsigned)el * 2;

  float m = -INFINITY, den = 0.f, acc0 = 0.f, acc1 = 0.f;

  for (int start = 0; start < deg; start += 32) {
    const int k = start + el;
    const bool vld = k < deg;
    const int s = vld ? col[base + k] : 0;
    float al = -INFINITY;
    if (vld) {
      const float t = siv + sj_g[(size_t)s * H + hl];
      al = (t > 0.f) ? t : 0.2f * t;
    }
    float cm = al;
#pragma unroll
    for (int o = 16; o; o >>= 1) cm = fmaxf(cm, __shfl_xor(cm, o, 64));
    const float nm = fmaxf(m, cm);
    const float r = __expf(m - nm);
    den *= r; acc0 *= r; acc1 *= r; m = nm;
    const float p = vld ? __expf(al - m) : 0.f;
    float ps = p;
#pragma unroll
    for (int o = 16; o; o >>= 1) ps += __shfl_xor(ps, o, 64);
    den += ps;

    const int cc = min(32, deg - start);
    int kk = 0;
    for (; kk + 4 * STEP <= cc; kk += 4 * STEP) {
      int sb[4]; float qb[4]; unsigned int uv[4];
#pragma unroll
      for (int u = 0; u < 4; ++u) {
        const int e = kk + u * STEP;
        sb[u] = __shfl(s, e + soff, 64);
        qb[u] = __shfl(p, e + qoff, 64);
      }
#pragma unroll
      for (int u = 0; u < 4; ++u)
        uv[u] = *reinterpret_cast<const unsigned int*>(xh + (size_t)sb[u] * HC + loff);
#pragma unroll
      for (int u = 0; u < 4; ++u) {
        uf32 lo, hi;
        lo.u = uv[u] << 16;
        hi.u = uv[u] & 0xffff0000u;
        acc0 = fmaf(qb[u], lo.f, acc0);
        acc1 = fmaf(qb[u], hi.f, acc1);
      }
    }
    for (; kk < cc; kk += STEP) {
      const int sb = __shfl(s, kk + soff, 64);
      const float qb = __shfl(p, kk + qoff, 64);
      const unsigned int uv = *reinterpret_cast<const unsigned int*>(xh + (size_t)sb * HC + loff);
      uf32 lo, hi;
      lo.u = uv << 16;
      hi.u = uv & 0xffff0000u;
      acc0 = fmaf(qb, lo.f, acc0);
      acc1 = fmaf(qb, hi.f, acc1);
    }
  }

  if (H == 2) {
    const float invd = 1.f / (den + 1e-16f);
    float v0 = acc0 * invd, v1 = acc1 * invd;
    v0 = (v0 > 0.f) ? v0 : expm1f(v0);
    v1 = (v1 > 0.f) ? v1 : expm1f(v1);
    if (OBF) {
      unsigned int pk = ((unsigned int)f2b(v1) << 16) | (unsigned int)f2b(v0);
      *reinterpret_cast<unsigned int*>((unsigned short*)out + (size_t)n * 128 + lane * 2) = pk;
    } else {
      float2 o; o.x = v0; o.y = v1;
      *reinterpret_cast<float2*>((float*)out + (size_t)n * 128 + lane * 2) = o;
    }
  } else {
    acc0 += __shfl_xor(acc0, 32, 64);
    acc1 += __shfl_xor(acc1, 32, 64);
    if (lane < 32) {
      const float invd = 1.f / (den + 1e-16f);
      float v0 = acc0 * invd, v1 = acc1 * invd;
      v0 = (v0 > 0.f) ? v0 : expm1f(v0);
      v1 = (v1 > 0.f) ? v1 : expm1f(v1);
      if (OBF) {
        unsigned int pk = ((unsigned int)f2b(v1) << 16) | (unsigned int)f2b(v0);
        *reinterpret_cast<unsigned int*>((unsigned short*)out + (size_t)n * 64 + el * 2) = pk;
      } else {
        float2 o; o.x = v0; o.y = v1;
        *reinterpret_cast<float2*>((float*)out + (size_t)n * 64 + el * 2) = o;
      }
    }
  }
}

// ---------------- launch ----------------
extern "C" void kernel_launch(void* const* d_in, const int* in_sizes, int n_in,
                              void* d_out, int out_size, void* d_ws, size_t ws_size,
                              hipStream_t stream) {
  const float* x     = (const float*)d_in[0];
  const int*   ei    = (const int*)d_in[1];
  const float* emb_w = (const float*)d_in[2];
  const float* emb_b = (const float*)d_in[3];
  const float* w0    = (const float*)d_in[4];
  const float* a0    = (const float*)d_in[5];
  const float* w1    = (const float*)d_in[6];
  const float* a1    = (const float*)d_in[7];
  const float* w2    = (const float*)d_in[8];
  const float* a2    = (const float*)d_in[9];

  const int IN_CH = 128;
  int N  = in_sizes[0] / IN_CH;   // 50000
  int E0 = in_sizes[1] / 2;       // 800000
  int E  = E0 + N;                // with self-loops

  // workspace carve (256B aligned)
  char* p = (char*)d_ws;
  auto alloc = [&](size_t bytes) -> char* {
    char* r = p;
    p += (bytes + 255) & ~(size_t)255;
    return r;
  };
  unsigned short* hA  = (unsigned short*)alloc((size_t)N * 128 * 2);
  unsigned short* hB  = (unsigned short*)alloc((size_t)N * 128 * 2);
  unsigned short* xhb = (unsigned short*)alloc((size_t)N * 128 * 2);
  float* si   = (float*)alloc((size_t)N * 2 * 4);
  float* sj   = (float*)alloc((size_t)N * 2 * 4);
  unsigned short* packE = (unsigned short*)alloc(128 * 64 * 2);
  unsigned short* pack0 = (unsigned short*)alloc(2 * 64 * 64 * 2);
  unsigned short* pack1 = (unsigned short*)alloc(2 * 128 * 64 * 2);
  unsigned short* pack2 = (unsigned short*)alloc(128 * 64 * 2);
  int* rp    = (int*)alloc((size_t)(N + 1) * 4);
  int* cnt   = (int*)alloc((size_t)N * 4);
  int* cnt8  = (int*)alloc((size_t)8 * N * 4);
  int* base8 = (int*)alloc((size_t)8 * N * 4);
  int* rb8   = (int*)alloc((size_t)8 * N * 4);
  unsigned short* lpos = (unsigned short*)alloc((size_t)E * 2);
  int* col   = (int*)alloc((size_t)E * 4);
  int* part  = (int*)alloc(1024);

  dim3 blk(256);
  int gN = (N + 255) / 256;     // 196
  int gE = (E + 255) / 256;

  // CSR build (atomic-light)
  zero8<<<(8 * N + 255) / 256, blk, 0, stream>>>(cnt8, 8 * N);
  hist8<<<gE, blk, 0, stream>>>(ei, cnt8, lpos, E0, N);
  fold8<<<gN, blk, 0, stream>>>(cnt8, base8, cnt, part, N);
  scan_carry<<<1, blk, 0, stream>>>(part, gN);
  scan3<<<gN, blk, 0, stream>>>(cnt, part, rp, N, E);
  addrp<<<dim3(gN, 8), blk, 0, stream>>>(rp, base8, rb8, N);
  fillx<<<gE, blk, 0, stream>>>(ei, rb8, lpos, col, E0, N);

  // weight packs (bf16 fragment layout)
  pack_w<<<dim3(32, 1), blk, 0, stream>>>(emb_w, packE, 128, 1, 128, 0);       // transpose
  pack_w<<<dim3(16, 2), blk, 0, stream>>>(w0, pack0, 64, 64, 1, 64 * 64);
  pack_w<<<dim3(32, 2), blk, 0, stream>>>(w1, pack1, 128, 64, 1, 128 * 64);
  pack_w<<<dim3(32, 1), blk, 0, stream>>>(w2, pack2, 128, 64, 1, 0);

  int gR = (N + 63) / 64;  // 782

  // embedding: x fp32 -> hA bf16 (+bias)
  gemm_mfma<128, 1, false, true, false, true><<<dim3(gR, 1), blk, 0, stream>>>(
      x, packE, emb_b, nullptr, hA, nullptr, nullptr, N);

  // layer 0: F=64, H=2 (bf16 in/out + scores)
  gemm_mfma<64, 2, true, false, true, true><<<dim3(gR, 2), blk, 0, stream>>>(
      hA, pack0, nullptr, a0, xhb, si, sj, N);
  agg_kernel<2, true><<<(N + 3) / 4, blk, 0, stream>>>(xhb, si, sj, rp, col, hB, N);

  // layer 1: F=128, H=2
  gemm_mfma<128, 2, true, false, true, true><<<dim3(gR, 2), blk, 0, stream>>>(
      hB, pack1, nullptr, a1, xhb, si, sj, N);
  agg_kernel<2, true><<<(N + 3) / 4, blk, 0, stream>>>(xhb, si, sj, rp, col, hA, N);

  // layer 2: F=128, H=1 -> output fp32
  gemm_mfma<128, 1, true, false, true, true><<<dim3(gR, 1), blk, 0, stream>>>(
      hA, pack2, nullptr, a2, xhb, si, sj, N);
  agg_kernel<1, false><<<(N + 3) / 4, blk, 0, stream>>>(xhb, si, sj, rp, col, (float*)d_out, N);
}

// Round 9
// 205.712 us; speedup vs baseline: 2.7684x; 1.0479x over previous
//
#include <hip/hip_runtime.h>
#include <math.h>

typedef __attribute__((ext_vector_type(8))) short short8v;   // 8 bf16 (4 VGPR)
typedef __attribute__((ext_vector_type(4))) float float4v;   // MFMA C/D frag

union uf32 { unsigned int u; float f; };

__device__ __forceinline__ unsigned short f2b(float f) {  // fp32 -> bf16 RNE
  uf32 v; v.f = f;
  unsigned int u = v.u;
  return (unsigned short)((u + 0x7fffu + ((u >> 16) & 1u)) >> 16);
}

// ================= CSR build (XCD-local atomics, atomic-free scatter) =======
__global__ void zero8(int* __restrict__ p, int n) {
  int i = blockIdx.x * 256 + threadIdx.x;
  if (i < n) p[i] = 0;
}

// Per-virtual-XCD histogram; records each edge's local position (removes the
// atomic from the fill pass). vx = blockIdx.x & 7 matches the default
// round-robin block->XCD mapping, so atomics on cnt8[vx] stay XCD-local.
__global__ void hist8(const int* __restrict__ ei, int* __restrict__ cnt8,
                      unsigned short* __restrict__ lpos, int E0, int N) {
  int e = blockIdx.x * 256 + threadIdx.x;
  if (e >= E0 + N) return;
  int vx = blockIdx.x & 7;
  int d = (e < E0) ? ei[E0 + e] : (e - E0);
  lpos[e] = (unsigned short)atomicAdd(&cnt8[vx * N + d], 1);
}

// Fold per-XCD counts -> total degree + per-XCD exclusive base; fused
// block-reduction of degrees into part[].
__global__ void fold8(const int* __restrict__ cnt8, int* __restrict__ base8,
                      int* __restrict__ cnt, int* __restrict__ part, int N) {
  __shared__ int lds[256];
  int d = blockIdx.x * 256 + threadIdx.x;
  int run = 0;
  if (d < N) {
#pragma unroll
    for (int x = 0; x < 8; ++x) {
      int t = cnt8[x * N + d];
      base8[x * N + d] = run;
      run += t;
    }
    cnt[d] = run;
  }
  lds[threadIdx.x] = (d < N) ? run : 0;
  __syncthreads();
  for (int o = 128; o; o >>= 1) {
    if (threadIdx.x < o) lds[threadIdx.x] += lds[threadIdx.x + o];
    __syncthreads();
  }
  if (threadIdx.x == 0) part[blockIdx.x] = lds[0];
}

// single-block exclusive scan with carry (handles any nb)
__global__ void scan_carry(int* __restrict__ part, int nb) {
  __shared__ int lds[256];
  __shared__ int carry;
  if (threadIdx.x == 0) carry = 0;
  __syncthreads();
  for (int t0 = 0; t0 < nb; t0 += 256) {
    int t = t0 + threadIdx.x;
    int v = (t < nb) ? part[t] : 0;
    lds[threadIdx.x] = v;
    __syncthreads();
    for (int o = 1; o < 256; o <<= 1) {
      int x = (threadIdx.x >= o) ? lds[threadIdx.x - o] : 0;
      __syncthreads();
      lds[threadIdx.x] += x;
      __syncthreads();
    }
    if (t < nb) part[t] = carry + lds[threadIdx.x] - v;  // exclusive
    __syncthreads();
    if (threadIdx.x == 255) carry += lds[255];
    __syncthreads();
  }
}

// rp[] scan + fused rb8[x][d] = rp[d] + base8[x][d]
__global__ void scan3(const int* __restrict__ cnt, const int* __restrict__ part,
                      const int* __restrict__ base8, int* __restrict__ rp,
                      int* __restrict__ rb8, int N, int E) {
  __shared__ int lds[256];
  int t = threadIdx.x;
  int idx = blockIdx.x * 256 + t;
  int v = (idx < N) ? cnt[idx] : 0;
  lds[t] = v;
  __syncthreads();
  for (int o = 1; o < 256; o <<= 1) {
    int x = (t >= o) ? lds[t - o] : 0;
    __syncthreads();
    lds[t] += x;
    __syncthreads();
  }
  if (idx < N) {
    const int rpv = part[blockIdx.x] + lds[t] - v;
    rp[idx] = rpv;
#pragma unroll
    for (int x = 0; x < 8; ++x) rb8[x * N + idx] = rpv + base8[x * N + idx];
  }
  if (blockIdx.x == 0 && t == 0) rp[N] = E;
}

// atomic-free scatter: same grid/vx mapping as hist8
__global__ void fillx(const int* __restrict__ ei, const int* __restrict__ rb8,
                      const unsigned short* __restrict__ lpos,
                      int* __restrict__ col, int E0, int N) {
  int e = blockIdx.x * 256 + threadIdx.x;
  if (e >= E0 + N) return;
  int vx = blockIdx.x & 7;
  int s, d;
  if (e < E0) { s = ei[e]; d = ei[E0 + e]; }
  else        { s = e - E0; d = s; }
  col[rb8[vx * N + d] + lpos[e]] = s;
}

// ---------------- all weight packs in one launch ----------------
// fp32 [h][f][c] (strided) -> bf16 MFMA B-frags, element order
// ((kk*4+ct)*4+g)*128 + col*8 + j with f=kk*32+g*8+j, c=ct*16+col.
__global__ void pack_all(const float* __restrict__ emb_w, const float* __restrict__ w0,
                         const float* __restrict__ w1, const float* __restrict__ w2,
                         unsigned short* __restrict__ pE, unsigned short* __restrict__ p0,
                         unsigned short* __restrict__ p1, unsigned short* __restrict__ p2) {
  int b = blockIdx.x;
  const float* w; unsigned short* bp;
  int F, sf, sc, h;
  if (b < 32)       { w = emb_w; bp = pE; F = 128; sf = 1;  sc = 128; h = 0; }
  else if (b < 64)  { b -= 32;  w = w0; bp = p0; F = 64;  sf = 64; sc = 1; h = b / 16; b %= 16; }
  else if (b < 128) { b -= 64;  w = w1; bp = p1; F = 128; sf = 64; sc = 1; h = b / 32; b %= 32; }
  else              { b -= 128; w = w2; bp = p2; F = 128; sf = 64; sc = 1; h = 0; }
  int i = b * 256 + threadIdx.x;
  if (i >= F * 64) return;
  int j = i & 7, colc = (i >> 3) & 15, g = (i >> 7) & 3, ct = (i >> 9) & 3, kk = i >> 11;
  int f = kk * 32 + g * 8 + j;
  int c = ct * 16 + colc;
  float v = w[(size_t)h * F * 64 + (size_t)f * sf + (size_t)c * sc];
  bp[(size_t)h * F * 64 + i] = f2b(v);
}

// ---------------- MFMA GEMM + attention scores (all heads per block) --------
// Block: 256 threads (4 waves), 64-row tile; loops h=0..H-1 with A-frags held
// in registers (A staged ONCE for both heads). B-frags from packed global
// (L2-hot). mfma_f32_16x16x32_bf16, fp32 acc.
// C/D: col = lane&15, row = (lane>>4)*4 + reg.
template <int F, int H, bool SCORES, bool BIAS, bool IBF, bool OBF>
__global__ __launch_bounds__(256) void gemm_mfma(
    const void* __restrict__ in, const unsigned short* __restrict__ bp,
    const float* __restrict__ bias, const float* __restrict__ a,
    void* __restrict__ xh_out, float* __restrict__ si, float* __restrict__ sj,
    int nrows) {
  constexpr int SA = F + 8;  // ushort stride, row base stays 16B aligned
  constexpr int NK = F / 32;
  constexpr int HC = H * 64;
  __shared__ __align__(16) unsigned short A_lds[64 * SA];

  const int tid = threadIdx.x;
  const int lane = tid & 63;
  const int wv = tid >> 6;
  const int n0 = blockIdx.x * 64;

  if (IBF) {  // bf16 input: straight ushort8 copies
    const unsigned short* inb = (const unsigned short*)in;
    constexpr int NCH = 64 * F / 8;
#pragma unroll
    for (int i0 = 0; i0 < NCH; i0 += 256) {
      const int i = i0 + tid;
      const int row = i / (F / 8);
      const int c8 = i % (F / 8);
      int rg = n0 + row;
      if (rg >= nrows) rg = nrows - 1;
      const short8v v = *reinterpret_cast<const short8v*>(inb + (size_t)rg * F + c8 * 8);
      *reinterpret_cast<short8v*>(A_lds + row * SA + c8 * 8) = v;
    }
  } else {    // fp32 input: convert while staging
    const float* inf = (const float*)in;
    constexpr int NCH = 64 * F / 4;
#pragma unroll
    for (int i0 = 0; i0 < NCH; i0 += 256) {
      const int i = i0 + tid;
      const int row = i / (F / 4);
      const int c4 = i % (F / 4);
      int rg = n0 + row;
      if (rg >= nrows) rg = nrows - 1;
      const float4 v = *reinterpret_cast<const float4*>(inf + (size_t)rg * F + c4 * 4);
      unsigned short* d = A_lds + row * SA + c4 * 4;
      d[0] = f2b(v.x); d[1] = f2b(v.y); d[2] = f2b(v.z); d[3] = f2b(v.w);
    }
  }
  __syncthreads();

  const int g = lane >> 4;
  const int cl = lane & 15;

  // A-frags in registers, shared across heads
  short8v af[NK];
  const unsigned short* ar = A_lds + (wv * 16 + cl) * SA + g * 8;
#pragma unroll
  for (int kk = 0; kk < NK; ++kk) af[kk] = *reinterpret_cast<const short8v*>(ar + kk * 32);

#pragma unroll
  for (int h = 0; h < H; ++h) {
    const unsigned short* __restrict__ bph = bp + (size_t)h * (F * 64);

    float4v acc[4];
#pragma unroll
    for (int ct = 0; ct < 4; ++ct) acc[ct] = (float4v){0.f, 0.f, 0.f, 0.f};

#pragma unroll
    for (int kk = 0; kk < NK; ++kk) {
#pragma unroll
      for (int ct = 0; ct < 4; ++ct) {
        const short8v bf = *reinterpret_cast<const short8v*>(
            bph + ((size_t)((kk * 4 + ct) * 4 + g)) * 128 + cl * 8);
        acc[ct] = __builtin_amdgcn_mfma_f32_16x16x32_bf16(af[kk], bf, acc[ct], 0, 0, 0);
      }
    }

    if (BIAS) {
#pragma unroll
      for (int ct = 0; ct < 4; ++ct) {
        const float b = bias[ct * 16 + cl];
#pragma unroll
        for (int reg = 0; reg < 4; ++reg) acc[ct][reg] += b;
      }
    }

    // store: lane holds col = ct*16+cl, rows wv*16 + g*4 + reg
#pragma unroll
    for (int ct = 0; ct < 4; ++ct) {
      const int c = ct * 16 + cl;
#pragma unroll
      for (int reg = 0; reg < 4; ++reg) {
        const int n = n0 + wv * 16 + g * 4 + reg;
        if (n < nrows) {
          const size_t idx = (size_t)n * HC + h * 64 + c;
          if (OBF) ((unsigned short*)xh_out)[idx] = f2b(acc[ct][reg]);
          else     ((float*)xh_out)[idx] = acc[ct][reg];
        }
      }
    }

    if (SCORES) {
      float pi[4] = {0.f, 0.f, 0.f, 0.f}, pj[4] = {0.f, 0.f, 0.f, 0.f};
#pragma unroll
      for (int ct = 0; ct < 4; ++ct) {
        const float av = a[h * 128 + ct * 16 + cl];
        const float bv = a[h * 128 + 64 + ct * 16 + cl];
#pragma unroll
        for (int reg = 0; reg < 4; ++reg) {
          pi[reg] = fmaf(acc[ct][reg], av, pi[reg]);
          pj[reg] = fmaf(acc[ct][reg], bv, pj[reg]);
        }
      }
#pragma unroll
      for (int reg = 0; reg < 4; ++reg) {
#pragma unroll
        for (int o = 8; o; o >>= 1) {  // reduce across the 16-lane col group
          pi[reg] += __shfl_xor(pi[reg], o, 64);
          pj[reg] += __shfl_xor(pj[reg], o, 64);
        }
      }
      if (cl == 0) {
#pragma unroll
        for (int reg = 0; reg < 4; ++reg) {
          const int n = n0 + wv * 16 + g * 4 + reg;
          if (n < nrows) {
            si[(size_t)n * H + h] = pi[reg];
            sj[(size_t)n * H + h] = pj[reg];
          }
        }
      }
    }
  }
}

// ---------------- per-node online-softmax aggregation (both heads / wave) ----
// One wave per node, 32-edge chunks. H==2: lane half = head; lane loads uint
// (2 bf16) -> one coalesced 256 B row read per edge. H==1: halves process two
// edges per iteration; final shfl_xor(32) combine. First chunk skips the
// online-rescale chain (common case: deg <= 32). OBF: write bf16 output.
template <int H, bool OBF>
__global__ __launch_bounds__(256) void agg_kernel(
    const unsigned short* __restrict__ xh, const float* __restrict__ si_g,
    const float* __restrict__ sj_g, const int* __restrict__ rp,
    const int* __restrict__ col, void* __restrict__ out, int N) {
  constexpr int HC = H * 64;
  const int lane = threadIdx.x & 63;
  const int n = blockIdx.x * 4 + (threadIdx.x >> 6);
  if (n >= N) return;
  const int el = lane & 31;
  const int hl = (H == 2) ? (lane >> 5) : 0;

  const int base = rp[n];
  const int deg = rp[n + 1] - base;
  const float siv = si_g[(size_t)n * H + hl];

  const int soff = (H == 1) ? (lane >> 5) : 0;
  const int qoff = (H == 1) ? (lane >> 5) : (lane & 32);
  constexpr int STEP = (H == 2) ? 1 : 2;
  const unsigned int loff = (H == 2) ? (unsigned)lane * 2 : (unsigned)el * 2;

  float m = 0.f, den = 0.f, acc0 = 0.f, acc1 = 0.f;

  for (int start = 0; start < deg; start += 32) {
    const int k = start + el;
    const bool vld = k < deg;
    const int s = vld ? col[base + k] : 0;
    float al = -INFINITY;
    if (vld) {
      const float t = siv + sj_g[(size_t)s * H + hl];
      al = (t > 0.f) ? t : 0.2f * t;
    }
    float cm = al;
#pragma unroll
    for (int o = 16; o; o >>= 1) cm = fmaxf(cm, __shfl_xor(cm, o, 64));
    if (start == 0) {
      m = cm;                      // first chunk: no rescale needed
    } else {
      const float nm = fmaxf(m, cm);
      const float r = __expf(m - nm);
      den *= r; acc0 *= r; acc1 *= r; m = nm;
    }
    const float p = vld ? __expf(al - m) : 0.f;
    float ps = p;
#pragma unroll
    for (int o = 16; o; o >>= 1) ps += __shfl_xor(ps, o, 64);
    den += ps;

    const int cc = min(32, deg - start);
    int kk = 0;
    for (; kk + 8 * STEP <= cc; kk += 8 * STEP) {
      int sb[8]; float qb[8]; unsigned int uv[8];
#pragma unroll
      for (int u = 0; u < 8; ++u) {
        const int e = kk + u * STEP;
        sb[u] = __shfl(s, e + soff, 64);
        qb[u] = __shfl(p, e + qoff, 64);
      }
#pragma unroll
      for (int u = 0; u < 8; ++u)
        uv[u] = *reinterpret_cast<const unsigned int*>(xh + (size_t)sb[u] * HC + loff);
#pragma unroll
      for (int u = 0; u < 8; ++u) {
        uf32 lo, hi;
        lo.u = uv[u] << 16;
        hi.u = uv[u] & 0xffff0000u;
        acc0 = fmaf(qb[u], lo.f, acc0);
        acc1 = fmaf(qb[u], hi.f, acc1);
      }
    }
    for (; kk + 4 * STEP <= cc; kk += 4 * STEP) {
      int sb[4]; float qb[4]; unsigned int uv[4];
#pragma unroll
      for (int u = 0; u < 4; ++u) {
        const int e = kk + u * STEP;
        sb[u] = __shfl(s, e + soff, 64);
        qb[u] = __shfl(p, e + qoff, 64);
      }
#pragma unroll
      for (int u = 0; u < 4; ++u)
        uv[u] = *reinterpret_cast<const unsigned int*>(xh + (size_t)sb[u] * HC + loff);
#pragma unroll
      for (int u = 0; u < 4; ++u) {
        uf32 lo, hi;
        lo.u = uv[u] << 16;
        hi.u = uv[u] & 0xffff0000u;
        acc0 = fmaf(qb[u], lo.f, acc0);
        acc1 = fmaf(qb[u], hi.f, acc1);
      }
    }
    for (; kk < cc; kk += STEP) {
      const int sb = __shfl(s, kk + soff, 64);
      const float qb = __shfl(p, kk + qoff, 64);
      const unsigned int uv = *reinterpret_cast<const unsigned int*>(xh + (size_t)sb * HC + loff);
      uf32 lo, hi;
      lo.u = uv << 16;
      hi.u = uv & 0xffff0000u;
      acc0 = fmaf(qb, lo.f, acc0);
      acc1 = fmaf(qb, hi.f, acc1);
    }
  }

  if (H == 2) {
    const float invd = 1.f / (den + 1e-16f);
    float v0 = acc0 * invd, v1 = acc1 * invd;
    v0 = (v0 > 0.f) ? v0 : expm1f(v0);
    v1 = (v1 > 0.f) ? v1 : expm1f(v1);
    if (OBF) {
      unsigned int pk = ((unsigned int)f2b(v1) << 16) | (unsigned int)f2b(v0);
      *reinterpret_cast<unsigned int*>((unsigned short*)out + (size_t)n * 128 + lane * 2) = pk;
    } else {
      float2 o; o.x = v0; o.y = v1;
      *reinterpret_cast<float2*>((float*)out + (size_t)n * 128 + lane * 2) = o;
    }
  } else {
    acc0 += __shfl_xor(acc0, 32, 64);
    acc1 += __shfl_xor(acc1, 32, 64);
    if (lane < 32) {
      const float invd = 1.f / (den + 1e-16f);
      float v0 = acc0 * invd, v1 = acc1 * invd;
      v0 = (v0 > 0.f) ? v0 : expm1f(v0);
      v1 = (v1 > 0.f) ? v1 : expm1f(v1);
      if (OBF) {
        unsigned int pk = ((unsigned int)f2b(v1) << 16) | (unsigned int)f2b(v0);
        *reinterpret_cast<unsigned int*>((unsigned short*)out + (size_t)n * 64 + el * 2) = pk;
      } else {
        float2 o; o.x = v0; o.y = v1;
        *reinterpret_cast<float2*>((float*)out + (size_t)n * 64 + el * 2) = o;
      }
    }
  }
}

// ---------------- launch ----------------
extern "C" void kernel_launch(void* const* d_in, const int* in_sizes, int n_in,
                              void* d_out, int out_size, void* d_ws, size_t ws_size,
                              hipStream_t stream) {
  const float* x     = (const float*)d_in[0];
  const int*   ei    = (const int*)d_in[1];
  const float* emb_w = (const float*)d_in[2];
  const float* emb_b = (const float*)d_in[3];
  const float* w0    = (const float*)d_in[4];
  const float* a0    = (const float*)d_in[5];
  const float* w1    = (const float*)d_in[6];
  const float* a1    = (const float*)d_in[7];
  const float* w2    = (const float*)d_in[8];
  const float* a2    = (const float*)d_in[9];

  const int IN_CH = 128;
  int N  = in_sizes[0] / IN_CH;   // 50000
  int E0 = in_sizes[1] / 2;       // 800000
  int E  = E0 + N;                // with self-loops

  // workspace carve (256B aligned)
  char* p = (char*)d_ws;
  auto alloc = [&](size_t bytes) -> char* {
    char* r = p;
    p += (bytes + 255) & ~(size_t)255;
    return r;
  };
  unsigned short* hA  = (unsigned short*)alloc((size_t)N * 128 * 2);
  unsigned short* hB  = (unsigned short*)alloc((size_t)N * 128 * 2);
  unsigned short* xhb = (unsigned short*)alloc((size_t)N * 128 * 2);
  float* si   = (float*)alloc((size_t)N * 2 * 4);
  float* sj   = (float*)alloc((size_t)N * 2 * 4);
  unsigned short* packE = (unsigned short*)alloc(128 * 64 * 2);
  unsigned short* pack0 = (unsigned short*)alloc(2 * 64 * 64 * 2);
  unsigned short* pack1 = (unsigned short*)alloc(2 * 128 * 64 * 2);
  unsigned short* pack2 = (unsigned short*)alloc(128 * 64 * 2);
  int* rp    = (int*)alloc((size_t)(N + 1) * 4);
  int* cnt   = (int*)alloc((size_t)N * 4);
  int* cnt8  = (int*)alloc((size_t)8 * N * 4);
  int* base8 = (int*)alloc((size_t)8 * N * 4);
  int* rb8   = (int*)alloc((size_t)8 * N * 4);
  unsigned short* lpos = (unsigned short*)alloc((size_t)E * 2);
  int* col   = (int*)alloc((size_t)E * 4);
  int* part  = (int*)alloc(1024);

  dim3 blk(256);
  int gN = (N + 255) / 256;     // 196
  int gE = (E + 255) / 256;

  // CSR build (atomic-light)
  zero8<<<(8 * N + 255) / 256, blk, 0, stream>>>(cnt8, 8 * N);
  hist8<<<gE, blk, 0, stream>>>(ei, cnt8, lpos, E0, N);
  fold8<<<gN, blk, 0, stream>>>(cnt8, base8, cnt, part, N);
  scan_carry<<<1, blk, 0, stream>>>(part, gN);
  scan3<<<gN, blk, 0, stream>>>(cnt, part, base8, rp, rb8, N, E);
  fillx<<<gE, blk, 0, stream>>>(ei, rb8, lpos, col, E0, N);

  // all weight packs in one launch
  pack_all<<<160, blk, 0, stream>>>(emb_w, w0, w1, w2, packE, pack0, pack1, pack2);

  int gR = (N + 63) / 64;  // 782

  // embedding: x fp32 -> hA bf16 (+bias)
  gemm_mfma<128, 1, false, true, false, true><<<gR, blk, 0, stream>>>(
      x, packE, emb_b, nullptr, hA, nullptr, nullptr, N);

  // layer 0: F=64, H=2 (both heads per block, bf16 in/out + scores)
  gemm_mfma<64, 2, true, false, true, true><<<gR, blk, 0, stream>>>(
      hA, pack0, nullptr, a0, xhb, si, sj, N);
  agg_kernel<2, true><<<(N + 3) / 4, blk, 0, stream>>>(xhb, si, sj, rp, col, hB, N);

  // layer 1: F=128, H=2
  gemm_mfma<128, 2, true, false, true, true><<<gR, blk, 0, stream>>>(
      hB, pack1, nullptr, a1, xhb, si, sj, N);
  agg_kernel<2, true><<<(N + 3) / 4, blk, 0, stream>>>(xhb, si, sj, rp, col, hA, N);

  // layer 2: F=128, H=1 -> output fp32
  gemm_mfma<128, 1, true, false, true, true><<<gR, blk, 0, stream>>>(
      hA, pack2, nullptr, a2, xhb, si, sj, N);
  agg_kernel<1, false><<<(N + 3) / 4, blk, 0, stream>>>(xhb, si, sj, rp, col, (float*)d_out, N);
}